// Round 1
// baseline (28002.972 us; speedup 1.0000x reference)
//
#include <hip/hip_runtime.h>
#include <hip/hip_cooperative_groups.h>

namespace cg = cooperative_groups;

typedef __attribute__((ext_vector_type(8))) short bf16x8;
typedef __attribute__((ext_vector_type(4))) float f32x4;

// Problem constants
// B=64, T=512, D=256, H=512, L=4, 4H=2048
#define NB 32   // main-kernel workgroups (8 per layer)
#define NT 512  // threads per workgroup (8 waves)

__device__ __forceinline__ unsigned short f2bf(float f) {
  unsigned int u = __float_as_uint(f);
  u += 0x7FFFu + ((u >> 16) & 1u);
  return (unsigned short)(u >> 16);
}

__device__ __forceinline__ float sigmoidf_(float x) {
  return 1.0f / (1.0f + __expf(-x));
}

// x [B,T,D] f32 -> xbf [T,B,D] bf16   (1,048,576 threads, 8 elems each)
__global__ void cvt_x_kernel(const float* __restrict__ x,
                             unsigned short* __restrict__ xbf) {
  int tid = blockIdx.x * 256 + threadIdx.x;
  int d8 = tid & 31;
  int b  = (tid >> 5) & 63;
  int t  = tid >> 11;
  const float* s = x + ((size_t)b * 512 + t) * 256 + d8 * 8;
  f32x4 v0 = *(const f32x4*)s;
  f32x4 v1 = *(const f32x4*)(s + 4);
  bf16x8 o;
  o[0] = (short)f2bf(v0[0]); o[1] = (short)f2bf(v0[1]);
  o[2] = (short)f2bf(v0[2]); o[3] = (short)f2bf(v0[3]);
  o[4] = (short)f2bf(v1[0]); o[5] = (short)f2bf(v1[1]);
  o[6] = (short)f2bf(v1[2]); o[7] = (short)f2bf(v1[3]);
  *(bf16x8*)(xbf + ((size_t)t * 64 + b) * 256 + d8 * 8) = o;
}

// W [2048, split] f32 + U [2048, 512] f32 -> dst [2048, K] bf16 (K = split+512)
__global__ void cvt_w_kernel(const float* __restrict__ W,
                             const float* __restrict__ U,
                             unsigned short* __restrict__ dst,
                             int K, int split) {
  int i8 = blockIdx.x * 256 + threadIdx.x;
  int idx = i8 * 8;
  int n = idx / K;
  int k = idx - n * K;
  const float* s = (k < split) ? (W + (size_t)n * split + k)
                               : (U + (size_t)n * 512 + (k - split));
  f32x4 v0 = *(const f32x4*)s;
  f32x4 v1 = *(const f32x4*)(s + 4);
  bf16x8 o;
  o[0] = (short)f2bf(v0[0]); o[1] = (short)f2bf(v0[1]);
  o[2] = (short)f2bf(v0[2]); o[3] = (short)f2bf(v0[3]);
  o[4] = (short)f2bf(v1[0]); o[5] = (short)f2bf(v1[1]);
  o[6] = (short)f2bf(v1[2]); o[7] = (short)f2bf(v1[3]);
  *(bf16x8*)(dst + (size_t)n * K + k) = o;
}

__global__ void bias_kernel(const float* __restrict__ bw,
                            const float* __restrict__ bu,
                            float* __restrict__ dst) {
  int i = blockIdx.x * 256 + threadIdx.x;  // 2048
  dst[i] = bw[i] + bu[i];
}

__global__ void zero_kernel(f32x4* __restrict__ p) {
  int i = blockIdx.x * 256 + threadIdx.x;  // 32768 -> 512KB
  f32x4 z = {0.f, 0.f, 0.f, 0.f};
  p[i] = z;
}

// Main persistent wavefront LSTM kernel.
// Grid: 32 wgs x 512 threads. wg = layer*8 + w ; wg owns h-cols [w*64, w*64+64).
// Wave v (8 per wg): vm = v&1 (batch half: rows vm*32..+31), vn = v>>1 (16 h-cols).
// Each wave computes z at its 16 h-cols for all 4 gates (cols +{0,512,1024,1536}),
// keeps c-state in registers.
__global__ void __launch_bounds__(NT, 1)
lstm_main(const unsigned short* __restrict__ xbf,
          const unsigned short* __restrict__ wc0,
          const unsigned short* __restrict__ wc1,
          const unsigned short* __restrict__ wc2,
          const unsigned short* __restrict__ wc3,
          const float* __restrict__ bias,
          unsigned short* __restrict__ hbuf,
          float* __restrict__ out) {
  cg::grid_group grid = cg::this_grid();

  const int wg    = blockIdx.x;
  const int layer = wg >> 3;
  const int w     = wg & 7;
  const int tid   = threadIdx.x;
  const int lane  = tid & 63;
  const int wv    = tid >> 6;
  const int l15   = lane & 15;
  const int lhi   = lane >> 4;
  const int vm    = wv & 1;
  const int vn    = wv >> 1;
  const int hcol  = w * 64 + vn * 16 + l15;   // this lane's h-column
  const int K     = (layer == 0) ? 768 : 1024;
  const int split = (layer == 0) ? 256 : 512;
  const int s1    = (layer == 0) ? 256 : 512; // row stride of region-1 A
  const unsigned short* wc =
      (layer == 0) ? wc0 : (layer == 1) ? wc1 : (layer == 2) ? wc2 : wc3;

  const unsigned short* brow[4];
  float bv[4];
#pragma unroll
  for (int g = 0; g < 4; ++g) {
    brow[g] = wc + (size_t)(g * 512 + hcol) * K + lhi * 8;
    bv[g]   = bias[layer * 2048 + g * 512 + hcol];
  }

  float creg[2][4];
#pragma unroll
  for (int m = 0; m < 2; ++m)
#pragma unroll
    for (int r = 0; r < 4; ++r) creg[m][r] = 0.f;

  const int rowA0 = vm * 32 + l15;  // A-frag row for m-tile 0

  for (int s = 0; s < 515; ++s) {
    int t = s - layer;
    if (t >= 0 && t < 512) {
      const int rp = (s + 1) & 1;  // read parity (written last superstep)
      const int wp = s & 1;        // write parity
      const unsigned short* p1 =
          (layer == 0) ? (xbf + (size_t)t * 16384)
                       : (hbuf + ((size_t)(layer - 1) * 2 + rp) * 32768);
      const unsigned short* p2 = hbuf + ((size_t)layer * 2 + rp) * 32768;

      f32x4 acc[2][4];
      const f32x4 z4 = {0.f, 0.f, 0.f, 0.f};
#pragma unroll
      for (int m = 0; m < 2; ++m)
#pragma unroll
        for (int g = 0; g < 4; ++g) acc[m][g] = z4;

      const int c1 = split >> 5;
      const int c2 = K >> 5;
      const unsigned short* a10 = p1 + lhi * 8 + (size_t)rowA0 * s1;
      const unsigned short* a11 = a10 + (size_t)16 * s1;
      const unsigned short* a20 = p2 + lhi * 8 + (size_t)rowA0 * 512;
      const unsigned short* a21 = a20 + 16 * 512;

#pragma unroll 4
      for (int c = 0; c < c1; ++c) {
        bf16x8 av0 = *(const bf16x8*)(a10 + c * 32);
        bf16x8 av1 = *(const bf16x8*)(a11 + c * 32);
#pragma unroll
        for (int g = 0; g < 4; ++g) {
          bf16x8 bb = *(const bf16x8*)(brow[g] + c * 32);
          acc[0][g] = __builtin_amdgcn_mfma_f32_16x16x32_bf16(av0, bb, acc[0][g], 0, 0, 0);
          acc[1][g] = __builtin_amdgcn_mfma_f32_16x16x32_bf16(av1, bb, acc[1][g], 0, 0, 0);
        }
      }
#pragma unroll 4
      for (int c = c1; c < c2; ++c) {
        int o2 = c * 32 - split;
        bf16x8 av0 = *(const bf16x8*)(a20 + o2);
        bf16x8 av1 = *(const bf16x8*)(a21 + o2);
#pragma unroll
        for (int g = 0; g < 4; ++g) {
          bf16x8 bb = *(const bf16x8*)(brow[g] + c * 32);
          acc[0][g] = __builtin_amdgcn_mfma_f32_16x16x32_bf16(av0, bb, acc[0][g], 0, 0, 0);
          acc[1][g] = __builtin_amdgcn_mfma_f32_16x16x32_bf16(av1, bb, acc[1][g], 0, 0, 0);
        }
      }

      unsigned short* hw = hbuf + ((size_t)layer * 2 + wp) * 32768;
#pragma unroll
      for (int m = 0; m < 2; ++m) {
#pragma unroll
        for (int r = 0; r < 4; ++r) {
          int bidx = vm * 32 + m * 16 + lhi * 4 + r;  // batch row
          float fg = sigmoidf_(acc[m][0][r] + bv[0]);
          float ig = sigmoidf_(acc[m][1][r] + bv[1]);
          float og = sigmoidf_(acc[m][2][r] + bv[2]);
          float gg = tanhf(acc[m][3][r] + bv[3]);
          float cn = fg * creg[m][r] + ig * gg;
          creg[m][r] = cn;
          float h = og * tanhf(cn);
          hw[(size_t)bidx * 512 + hcol] = f2bf(h);
          if (layer == 3)
            out[(size_t)bidx * 262144 + (size_t)t * 512 + hcol] = h;
          if (t == 511) {
            out[16777216 + ((size_t)layer * 64 + bidx) * 512 + hcol] = h;
            out[16777216 + 131072 + ((size_t)layer * 64 + bidx) * 512 + hcol] = cn;
          }
        }
      }
    }
    __threadfence();
    grid.sync();
  }
}

extern "C" void kernel_launch(void* const* d_in, const int* in_sizes, int n_in,
                              void* d_out, int out_size, void* d_ws, size_t ws_size,
                              hipStream_t stream) {
  const float* x = (const float*)d_in[0];
  const float *W[4], *U[4], *bw[4], *bu[4];
  for (int l = 0; l < 4; ++l) {
    W[l]  = (const float*)d_in[1 + 4 * l];
    U[l]  = (const float*)d_in[2 + 4 * l];
    bw[l] = (const float*)d_in[3 + 4 * l];
    bu[l] = (const float*)d_in[4 + 4 * l];
  }

  char* ws = (char*)d_ws;
  unsigned short* xbf = (unsigned short*)(ws + 0);          // 16,777,216 B
  unsigned short* wcat0 = (unsigned short*)(ws + 16777216); //  3,145,728 B
  unsigned short* wcat1 = (unsigned short*)(ws + 19922944); //  4,194,304 B
  unsigned short* wcat2 = (unsigned short*)(ws + 24117248); //  4,194,304 B
  unsigned short* wcat3 = (unsigned short*)(ws + 28311552); //  4,194,304 B
  float*          biasp = (float*)(ws + 32505856);          //     32,768 B
  unsigned short* hbuf  = (unsigned short*)(ws + 32538624); //    524,288 B
  float* out = (float*)d_out;

  // Prep: convert/transposes (all parallel, ~35us total)
  cvt_x_kernel<<<4096, 256, 0, stream>>>(x, xbf);
  cvt_w_kernel<<<768, 256, 0, stream>>>(W[0], U[0], wcat0, 768, 256);
  cvt_w_kernel<<<1024, 256, 0, stream>>>(W[1], U[1], wcat1, 1024, 512);
  cvt_w_kernel<<<1024, 256, 0, stream>>>(W[2], U[2], wcat2, 1024, 512);
  cvt_w_kernel<<<1024, 256, 0, stream>>>(W[3], U[3], wcat3, 1024, 512);
  bias_kernel<<<8, 256, 0, stream>>>(bw[0], bu[0], biasp + 0 * 2048);
  bias_kernel<<<8, 256, 0, stream>>>(bw[1], bu[1], biasp + 1 * 2048);
  bias_kernel<<<8, 256, 0, stream>>>(bw[2], bu[2], biasp + 2 * 2048);
  bias_kernel<<<8, 256, 0, stream>>>(bw[3], bu[3], biasp + 3 * 2048);
  zero_kernel<<<128, 256, 0, stream>>>((f32x4*)hbuf);

  // Main persistent wavefront kernel (cooperative: needs grid.sync)
  void* args[8];
  args[0] = (void*)&xbf;
  args[1] = (void*)&wcat0;
  args[2] = (void*)&wcat1;
  args[3] = (void*)&wcat2;
  args[4] = (void*)&wcat3;
  args[5] = (void*)&biasp;
  args[6] = (void*)&hbuf;
  args[7] = (void*)&out;
  hipLaunchCooperativeKernel((void*)lstm_main, dim3(NB), dim3(NT), args, 0, stream);
}

// Round 2
// 19678.871 us; speedup vs baseline: 1.4230x; 1.4230x over previous
//
#include <hip/hip_runtime.h>

typedef __attribute__((ext_vector_type(8))) short bf16x8;
typedef __attribute__((ext_vector_type(4))) float f32x4;

// B=64, T=512, D=256, H=512, L=4, 4H=2048
#define NT 512
#define RING 8

__device__ __forceinline__ unsigned short f2bf(float f) {
  unsigned int u = __float_as_uint(f);
  u += 0x7FFFu + ((u >> 16) & 1u);
  return (unsigned short)(u >> 16);
}

__device__ __forceinline__ float sigmoidf_(float x) {
  return 1.0f / (1.0f + __expf(-x));
}

// Coherent (LLC) 16B load: bypass L1+L2 so cross-XCD h-exchange is seen
// without any cache invalidation (weights stay L2-resident).
__device__ __forceinline__ f32x4 ld16_coh(const void* p) {
  f32x4 r;
  asm volatile("global_load_dwordx4 %0, %1, off sc0 sc1" : "=v"(r) : "v"(p));
  return r;
}
// Coherent 2B store (write-through to LLC).
__device__ __forceinline__ void st2_coh(void* p, unsigned int v) {
  asm volatile("global_store_short %0, %1, off sc0 sc1" :: "v"(p), "v"(v) : "memory");
}
__device__ __forceinline__ void wait_vm0() {
  asm volatile("s_waitcnt vmcnt(0)" ::: "memory");
  __builtin_amdgcn_sched_barrier(0);
}

// x [B,T,D] f32 -> xbf [T,B,D] bf16
__global__ void cvt_x_kernel(const float* __restrict__ x,
                             unsigned short* __restrict__ xbf) {
  int tid = blockIdx.x * 256 + threadIdx.x;
  int d8 = tid & 31;
  int b  = (tid >> 5) & 63;
  int t  = tid >> 11;
  const float* s = x + ((size_t)b * 512 + t) * 256 + d8 * 8;
  f32x4 v0 = *(const f32x4*)s;
  f32x4 v1 = *(const f32x4*)(s + 4);
  bf16x8 o;
  o[0] = (short)f2bf(v0[0]); o[1] = (short)f2bf(v0[1]);
  o[2] = (short)f2bf(v0[2]); o[3] = (short)f2bf(v0[3]);
  o[4] = (short)f2bf(v1[0]); o[5] = (short)f2bf(v1[1]);
  o[6] = (short)f2bf(v1[2]); o[7] = (short)f2bf(v1[3]);
  *(bf16x8*)(xbf + ((size_t)t * 64 + b) * 256 + d8 * 8) = o;
}

// W [2048, split] f32 + U [2048, 512] f32 -> dst [2048, K] bf16 (K = split+512)
__global__ void cvt_w_kernel(const float* __restrict__ W,
                             const float* __restrict__ U,
                             unsigned short* __restrict__ dst,
                             int K, int split) {
  int i8 = blockIdx.x * 256 + threadIdx.x;
  int idx = i8 * 8;
  int n = idx / K;
  int k = idx - n * K;
  const float* s = (k < split) ? (W + (size_t)n * split + k)
                               : (U + (size_t)n * 512 + (k - split));
  f32x4 v0 = *(const f32x4*)s;
  f32x4 v1 = *(const f32x4*)(s + 4);
  bf16x8 o;
  o[0] = (short)f2bf(v0[0]); o[1] = (short)f2bf(v0[1]);
  o[2] = (short)f2bf(v0[2]); o[3] = (short)f2bf(v0[3]);
  o[4] = (short)f2bf(v1[0]); o[5] = (short)f2bf(v1[1]);
  o[6] = (short)f2bf(v1[2]); o[7] = (short)f2bf(v1[3]);
  *(bf16x8*)(dst + (size_t)n * K + k) = o;
}

__global__ void bias_kernel(const float* __restrict__ bw,
                            const float* __restrict__ bu,
                            float* __restrict__ dst) {
  int i = blockIdx.x * 256 + threadIdx.x;  // 2048
  dst[i] = bw[i] + bu[i];
}

__global__ void zero_flags(unsigned int* __restrict__ p) {
  int i = blockIdx.x * 256 + threadIdx.x;  // 2048 flags
  p[i] = 0u;
}

// Persistent wavefront LSTM, flag-synced (no grid.sync).
// 32 wgs: wg = layer*8 + w. wg owns h-cols [w*64, w*64+64).
// Per step: poll flags -> LDS-stage A (inp tile + own-h tile, XOR-swizzled)
// -> MFMA against L2-resident weights -> gates -> coherent h store -> flag++.
__global__ void __launch_bounds__(NT, 1)
lstm_main(const unsigned short* __restrict__ xbf,
          const unsigned short* __restrict__ wc0,
          const unsigned short* __restrict__ wc1,
          const unsigned short* __restrict__ wc2,
          const unsigned short* __restrict__ wc3,
          const float* __restrict__ bias,
          unsigned short* __restrict__ hbuf,
          unsigned int* __restrict__ cnt,
          float* __restrict__ out) {
  extern __shared__ char smem[];

  const int wg    = blockIdx.x;
  const int layer = wg >> 3;
  const int w     = wg & 7;
  const int tid   = threadIdx.x;
  const int lane  = tid & 63;
  const int wv    = tid >> 6;
  const int l15   = lane & 15;
  const int lhi   = lane >> 4;
  const int vm    = wv & 1;
  const int vn    = wv >> 1;
  const int hcol  = w * 64 + vn * 16 + l15;
  const int K     = (layer == 0) ? 768 : 1024;
  const int c1    = (layer == 0) ? 8 : 16;     // Kin/32
  const int SIb   = (layer == 0) ? 512 : 1024; // inp-tile row bytes
  const int a2b   = (layer == 0) ? 32768 : 65536;
  const unsigned short* wc =
      (layer == 0) ? wc0 : (layer == 1) ? wc1 : (layer == 2) ? wc2 : wc3;

  const unsigned short* brow[4];
  float bv[4];
#pragma unroll
  for (int g = 0; g < 4; ++g) {
    brow[g] = wc + (size_t)(g * 512 + hcol) * K + lhi * 8;
    bv[g]   = bias[layer * 2048 + g * 512 + hcol];
  }

  float creg[2][4];
#pragma unroll
  for (int m = 0; m < 2; ++m)
#pragma unroll
    for (int r = 0; r < 4; ++r) creg[m][r] = 0.f;

  const int rb1_0 = (vm * 32 + l15) * SIb;
  const int rb1_1 = rb1_0 + 16 * SIb;
  const int rb2_0 = a2b + (vm * 32 + l15) * 1024;
  const int rb2_1 = rb2_0 + 16 * 1024;
  const int lh    = lhi * 16;
  const int mask  = (l15 & 7) << 4;

  for (int t = 0; t < 512; ++t) {
    // ---- 1. poll dependencies (tid 0 only) ----
    if (tid == 0) {
      if (layer > 0)
        while (__hip_atomic_load(&cnt[(layer - 1) * 512 + t],
                                 __ATOMIC_RELAXED, __HIP_MEMORY_SCOPE_AGENT) < 8u)
          __builtin_amdgcn_s_sleep(1);
      if (t > 0)
        while (__hip_atomic_load(&cnt[layer * 512 + t - 1],
                                 __ATOMIC_RELAXED, __HIP_MEMORY_SCOPE_AGENT) < 8u)
          __builtin_amdgcn_s_sleep(1);
      if (layer < 3 && t >= RING)
        while (__hip_atomic_load(&cnt[(layer + 1) * 512 + t - RING],
                                 __ATOMIC_RELAXED, __HIP_MEMORY_SCOPE_AGENT) < 8u)
          __builtin_amdgcn_s_sleep(1);
    }
    __syncthreads();

    // ---- 2. stage A operands into LDS (XOR-swizzled) ----
    if (layer == 0) {
      const unsigned short* srcI = xbf + (size_t)t * 16384;
      f32x4 vi[4], vh[8];
#pragma unroll
      for (int j = 0; j < 4; ++j)
        vi[j] = *(const f32x4*)(srcI + (size_t)(tid + j * 512) * 8);
      if (t > 0) {
        const unsigned short* srcH =
            hbuf + ((size_t)layer * RING + ((t - 1) & (RING - 1))) * 32768;
#pragma unroll
        for (int j = 0; j < 8; ++j)
          vh[j] = ld16_coh(srcH + (size_t)(tid + j * 512) * 8);
      }
      wait_vm0();
#pragma unroll
      for (int j = 0; j < 4; ++j) {
        int g = tid + j * 512;
        int row = g >> 5, cb = g & 31;
        *(f32x4*)(smem + row * 512 + ((cb * 16) ^ ((row & 7) << 4))) = vi[j];
      }
      if (t > 0) {
#pragma unroll
        for (int j = 0; j < 8; ++j) {
          int g = tid + j * 512;
          int row = g >> 6, cb = g & 63;
          *(f32x4*)(smem + 32768 + row * 1024 + ((cb * 16) ^ ((row & 7) << 4))) = vh[j];
        }
      }
    } else {
      const unsigned short* srcI =
          hbuf + ((size_t)(layer - 1) * RING + (t & (RING - 1))) * 32768;
      f32x4 vi[8], vh[8];
#pragma unroll
      for (int j = 0; j < 8; ++j)
        vi[j] = ld16_coh(srcI + (size_t)(tid + j * 512) * 8);
      if (t > 0) {
        const unsigned short* srcH =
            hbuf + ((size_t)layer * RING + ((t - 1) & (RING - 1))) * 32768;
#pragma unroll
        for (int j = 0; j < 8; ++j)
          vh[j] = ld16_coh(srcH + (size_t)(tid + j * 512) * 8);
      }
      wait_vm0();
#pragma unroll
      for (int j = 0; j < 8; ++j) {
        int g = tid + j * 512;
        int row = g >> 6, cb = g & 63;
        *(f32x4*)(smem + row * 1024 + ((cb * 16) ^ ((row & 7) << 4))) = vi[j];
      }
      if (t > 0) {
#pragma unroll
        for (int j = 0; j < 8; ++j) {
          int g = tid + j * 512;
          int row = g >> 6, cb = g & 63;
          *(f32x4*)(smem + 65536 + row * 1024 + ((cb * 16) ^ ((row & 7) << 4))) = vh[j];
        }
      }
    }
    __syncthreads();

    // ---- 3. GEMM: z = [inp | h] @ Wcat^T  (A from LDS, B from L2) ----
    f32x4 acc[2][4];
    const f32x4 z4 = {0.f, 0.f, 0.f, 0.f};
#pragma unroll
    for (int m = 0; m < 2; ++m)
#pragma unroll
      for (int g = 0; g < 4; ++g) acc[m][g] = z4;

#pragma unroll 4
    for (int c = 0; c < c1; ++c) {
      int off = (c * 64 + lh) ^ mask;
      bf16x8 av0 = *(const bf16x8*)(smem + rb1_0 + off);
      bf16x8 av1 = *(const bf16x8*)(smem + rb1_1 + off);
#pragma unroll
      for (int g = 0; g < 4; ++g) {
        bf16x8 bb = *(const bf16x8*)(brow[g] + c * 32);
        acc[0][g] = __builtin_amdgcn_mfma_f32_16x16x32_bf16(av0, bb, acc[0][g], 0, 0, 0);
        acc[1][g] = __builtin_amdgcn_mfma_f32_16x16x32_bf16(av1, bb, acc[1][g], 0, 0, 0);
      }
    }
    if (t > 0) {
#pragma unroll 4
      for (int c = 0; c < 16; ++c) {
        int off = (c * 64 + lh) ^ mask;
        bf16x8 av0 = *(const bf16x8*)(smem + rb2_0 + off);
        bf16x8 av1 = *(const bf16x8*)(smem + rb2_1 + off);
#pragma unroll
        for (int g = 0; g < 4; ++g) {
          bf16x8 bb = *(const bf16x8*)(brow[g] + (c1 + c) * 32);
          acc[0][g] = __builtin_amdgcn_mfma_f32_16x16x32_bf16(av0, bb, acc[0][g], 0, 0, 0);
          acc[1][g] = __builtin_amdgcn_mfma_f32_16x16x32_bf16(av1, bb, acc[1][g], 0, 0, 0);
        }
      }
    }

    // ---- 4. gates + state update + coherent h store ----
    unsigned short* hw =
        hbuf + ((size_t)layer * RING + (t & (RING - 1))) * 32768;
#pragma unroll
    for (int m = 0; m < 2; ++m) {
#pragma unroll
      for (int r = 0; r < 4; ++r) {
        int bidx = vm * 32 + m * 16 + lhi * 4 + r;
        float fg = sigmoidf_(acc[m][0][r] + bv[0]);
        float ig = sigmoidf_(acc[m][1][r] + bv[1]);
        float og = sigmoidf_(acc[m][2][r] + bv[2]);
        float gg = tanhf(acc[m][3][r] + bv[3]);
        float cn = fg * creg[m][r] + ig * gg;
        creg[m][r] = cn;
        float h = og * tanhf(cn);
        st2_coh(hw + (size_t)bidx * 512 + hcol, (unsigned int)f2bf(h));
        if (layer == 3)
          out[(size_t)bidx * 262144 + (size_t)t * 512 + hcol] = h;
        if (t == 511) {
          out[16777216 + ((size_t)layer * 64 + bidx) * 512 + hcol] = h;
          out[16777216 + 131072 + ((size_t)layer * 64 + bidx) * 512 + hcol] = cn;
        }
      }
    }
    wait_vm0();       // all coherent stores at LLC
    __syncthreads();  // whole wg done (also fences LDS reads vs next staging)

    // ---- 5. publish ----
    if (tid == 0)
      __hip_atomic_fetch_add(&cnt[layer * 512 + t], 1u,
                             __ATOMIC_RELAXED, __HIP_MEMORY_SCOPE_AGENT);
  }
}

extern "C" void kernel_launch(void* const* d_in, const int* in_sizes, int n_in,
                              void* d_out, int out_size, void* d_ws, size_t ws_size,
                              hipStream_t stream) {
  const float* x = (const float*)d_in[0];
  const float *W[4], *U[4], *bw[4], *bu[4];
  for (int l = 0; l < 4; ++l) {
    W[l]  = (const float*)d_in[1 + 4 * l];
    U[l]  = (const float*)d_in[2 + 4 * l];
    bw[l] = (const float*)d_in[3 + 4 * l];
    bu[l] = (const float*)d_in[4 + 4 * l];
  }

  char* ws = (char*)d_ws;
  unsigned short* xbf   = (unsigned short*)(ws + 0);        // 16,777,216
  unsigned short* wcat0 = (unsigned short*)(ws + 16777216); //  3,145,728
  unsigned short* wcat1 = (unsigned short*)(ws + 19922944); //  4,194,304
  unsigned short* wcat2 = (unsigned short*)(ws + 24117248); //  4,194,304
  unsigned short* wcat3 = (unsigned short*)(ws + 28311552); //  4,194,304
  float*          biasp = (float*)(ws + 32505856);          //     32,768
  unsigned short* hbuf  = (unsigned short*)(ws + 32538624); //  2,097,152 (4x8 ring)
  unsigned int*   cnt   = (unsigned int*)(ws + 34635776);   //      8,192
  float* out = (float*)d_out;

  cvt_x_kernel<<<4096, 256, 0, stream>>>(x, xbf);
  cvt_w_kernel<<<768, 256, 0, stream>>>(W[0], U[0], wcat0, 768, 256);
  cvt_w_kernel<<<1024, 256, 0, stream>>>(W[1], U[1], wcat1, 1024, 512);
  cvt_w_kernel<<<1024, 256, 0, stream>>>(W[2], U[2], wcat2, 1024, 512);
  cvt_w_kernel<<<1024, 256, 0, stream>>>(W[3], U[3], wcat3, 1024, 512);
  bias_kernel<<<8, 256, 0, stream>>>(bw[0], bu[0], biasp + 0 * 2048);
  bias_kernel<<<8, 256, 0, stream>>>(bw[1], bu[1], biasp + 1 * 2048);
  bias_kernel<<<8, 256, 0, stream>>>(bw[2], bu[2], biasp + 2 * 2048);
  bias_kernel<<<8, 256, 0, stream>>>(bw[3], bu[3], biasp + 3 * 2048);
  zero_flags<<<8, 256, 0, stream>>>(cnt);

  hipFuncSetAttribute((const void*)lstm_main,
                      hipFuncAttributeMaxDynamicSharedMemorySize, 131072);
  lstm_main<<<dim3(32), dim3(NT), 131072, stream>>>(
      xbf, wcat0, wcat1, wcat2, wcat3, biasp, hbuf, cnt, out);
}

// Round 4
// 3057.554 us; speedup vs baseline: 9.1586x; 6.4361x over previous
//
#include <hip/hip_runtime.h>

typedef __attribute__((ext_vector_type(8))) short bf16x8;
typedef __attribute__((ext_vector_type(4))) float f32x4;

// B=64, T=512, D=256, H=512, L=4, 4H=2048
// 32 wgs per layer (16 hcols each), 128 threads (2 waves) per wg.
#define WPL 32
#define NT 128
#define RING 8

__device__ __forceinline__ unsigned short f2bf(float f) {
  unsigned int u = __float_as_uint(f);
  u += 0x7FFFu + ((u >> 16) & 1u);
  return (unsigned short)(u >> 16);
}
// sigmoid(x) = 1/(1+2^(-x*log2e)) ; tanh(x) = 1 - 2/(1+2^(x*2*log2e))
__device__ __forceinline__ float sigmoid_fast(float x) {
  return __builtin_amdgcn_rcpf(1.0f + __builtin_amdgcn_exp2f(-1.4426950408889634f * x));
}
__device__ __forceinline__ float tanh_fast(float x) {
  return 1.0f - 2.0f * __builtin_amdgcn_rcpf(
                           1.0f + __builtin_amdgcn_exp2f(2.885390081777927f * x));
}
__device__ __forceinline__ void st2_coh(void* p, unsigned int v) {
  asm volatile("global_store_short %0, %1, off sc0 sc1" :: "v"(p), "v"(v) : "memory");
}
__device__ __forceinline__ void wait_vm0() {
  asm volatile("s_waitcnt vmcnt(0)" ::: "memory");
  __builtin_amdgcn_sched_barrier(0);
}
#define WAITVM(N)                                         \
  do {                                                    \
    asm volatile("s_waitcnt vmcnt(" #N ")" ::: "memory"); \
    __builtin_amdgcn_sched_barrier(0);                    \
  } while (0)

// ---------------- prep kernels ----------------

// x [B,T,D] f32 -> xfrag [T][c(8)][bt(4)][lane(64)][e(8)] bf16, lane-linear:
// value(b = bt*16 + (lane&15), d = c*32 + (lane>>4)*8 + e)
__global__ void cvt_x_kernel(const float* __restrict__ x,
                             unsigned short* __restrict__ xf) {
  int tid = blockIdx.x * 256 + threadIdx.x;  // 1,048,576
  int t     = tid >> 11;
  int inner = tid & 2047;
  int lane  = inner & 63;
  int bt    = (inner >> 6) & 3;
  int c     = inner >> 8;
  int b = bt * 16 + (lane & 15);
  int d = c * 32 + (lane >> 4) * 8;
  const float* s = x + ((size_t)b * 512 + t) * 256 + d;
  f32x4 v0 = *(const f32x4*)s;
  f32x4 v1 = *(const f32x4*)(s + 4);
  bf16x8 o;
  o[0] = (short)f2bf(v0[0]); o[1] = (short)f2bf(v0[1]);
  o[2] = (short)f2bf(v0[2]); o[3] = (short)f2bf(v0[3]);
  o[4] = (short)f2bf(v1[0]); o[5] = (short)f2bf(v1[1]);
  o[6] = (short)f2bf(v1[2]); o[7] = (short)f2bf(v1[3]);
  *(bf16x8*)(xf + (size_t)t * 16384 + (size_t)inner * 8) = o;
}

// W [2048,split] + U [2048,512] f32 -> wfrag per wg slice:
// [w(32)][g(4)][c(C2)][lane(64)][e(8)] bf16,
// value = row(g*512 + w*16 + (lane&15)), k(c*32 + (lane>>4)*8 + e)
__global__ void cvt_w_kernel(const float* __restrict__ W,
                             const float* __restrict__ U,
                             unsigned short* __restrict__ dst,
                             int C2, int split) {
  int tid = blockIdx.x * 256 + threadIdx.x;
  int lane = tid & 63;
  int c    = (tid >> 6) % C2;
  int rest = tid / (64 * C2);
  int g = rest & 3;
  int w = rest >> 2;
  int row = g * 512 + w * 16 + (lane & 15);
  int k   = c * 32 + (lane >> 4) * 8;
  const float* s = (k < split) ? (W + (size_t)row * split + k)
                               : (U + (size_t)row * 512 + (k - split));
  f32x4 v0 = *(const f32x4*)s;
  f32x4 v1 = *(const f32x4*)(s + 4);
  bf16x8 o;
  o[0] = (short)f2bf(v0[0]); o[1] = (short)f2bf(v0[1]);
  o[2] = (short)f2bf(v0[2]); o[3] = (short)f2bf(v0[3]);
  o[4] = (short)f2bf(v1[0]); o[5] = (short)f2bf(v1[1]);
  o[6] = (short)f2bf(v1[2]); o[7] = (short)f2bf(v1[3]);
  *(bf16x8*)(dst + (size_t)tid * 8) = o;
}

__global__ void bias_kernel(const float* __restrict__ bw,
                            const float* __restrict__ bu,
                            float* __restrict__ dst) {
  int i = blockIdx.x * 256 + threadIdx.x;  // 2048
  dst[i] = bw[i] + bu[i];
}

__global__ void zero_flags(unsigned int* __restrict__ p) {
  int i = blockIdx.x * 256 + threadIdx.x;  // 2048
  p[i] = 0u;
}

// ---------------- pipelined per-step GEMM ----------------
// A from global frag layout (coherent for h, cached for x), B from LDS frag
// layout. 3-phase-deep A pipeline with counted vmcnt; 2-deep B (LDS).
template <int C1, int C2, bool COH1>
__device__ __forceinline__ void gemm_run(const unsigned short* __restrict__ a1,
                                         const unsigned short* __restrict__ a2,
                                         const char* bg0, const char* bg1,
                                         const char* bg2, const char* bg3,
                                         int voffA, int vm, f32x4 acc[2][4]) {
  constexpr int NP = C2 / 4;  // phases of 4 k-chunks
  bf16x8 av[3][4][2];
  bf16x8 bb[2][4][4];
  const char* bgp[4] = {bg0, bg1, bg2, bg3};

  auto issueA_iter = [&](int cc, int s3, int i) {
#pragma unroll
    for (int m = 0; m < 2; ++m) {
      if (cc < C1) {
        int voff = voffA + (vm * 2 + m) * 1024 + cc * 4096;
        if constexpr (COH1)
          asm volatile("global_load_dwordx4 %0, %1, %2 sc0 sc1"
                       : "=v"(av[s3][i][m]) : "v"(voff), "s"(a1));
        else
          asm volatile("global_load_dwordx4 %0, %1, %2"
                       : "=v"(av[s3][i][m]) : "v"(voff), "s"(a1));
      } else {
        int voff = voffA + (vm * 2 + m) * 1024 + (cc - C1) * 4096;
        asm volatile("global_load_dwordx4 %0, %1, %2 sc0 sc1"
                     : "=v"(av[s3][i][m]) : "v"(voff), "s"(a2));
      }
    }
  };
  auto issueA_phase = [&](int q) {
#pragma unroll
    for (int i = 0; i < 4; ++i) issueA_iter(4 * q + i, q % 3, i);
  };
  auto loadB_phase = [&](int q) {
#pragma unroll
    for (int i = 0; i < 4; ++i)
#pragma unroll
      for (int g = 0; g < 4; ++g)
        bb[q & 1][i][g] = *(const bf16x8*)(bgp[g] + (4 * q + i) * 1024);
  };

  // prologue: up to 3 phases of A in flight, 1 phase of B
#pragma unroll
  for (int q = 0; q < 3; ++q)
    if (q < NP) issueA_phase(q);
  loadB_phase(0);

#pragma unroll
  for (int ph = 0; ph < NP; ++ph) {
    if (ph + 1 < NP) loadB_phase(ph + 1);
    if (ph < NP - 2) {
      WAITVM(16);
    } else if (ph == NP - 2) {
      WAITVM(8);
    } else {
      WAITVM(0);
    }
#pragma unroll
    for (int i = 0; i < 4; ++i)
#pragma unroll
      for (int g = 0; g < 4; ++g) {
        acc[0][g] = __builtin_amdgcn_mfma_f32_16x16x32_bf16(av[ph % 3][i][0],
                                                            bb[ph & 1][i][g],
                                                            acc[0][g], 0, 0, 0);
        acc[1][g] = __builtin_amdgcn_mfma_f32_16x16x32_bf16(av[ph % 3][i][1],
                                                            bb[ph & 1][i][g],
                                                            acc[1][g], 0, 0, 0);
      }
    if (ph + 3 < NP) issueA_phase(ph + 3);
  }
}

// ---------------- main persistent kernel ----------------
// grid 128: layer = bid>>5, w = bid&31 (hcols w*16..w*16+16).
// 2 waves: vm = wave id (batch half: 32 rows, 2 m-tiles each).
__global__ void __launch_bounds__(NT, 1)
lstm_main(const unsigned short* __restrict__ xfrag,
          const unsigned short* __restrict__ wf0,
          const unsigned short* __restrict__ wf1,
          const unsigned short* __restrict__ wf2,
          const unsigned short* __restrict__ wf3,
          const float* __restrict__ bias,
          unsigned short* __restrict__ hbuf,
          unsigned int* __restrict__ cnt,
          float* __restrict__ out) {
  extern __shared__ char smem[];

  const int bid   = blockIdx.x;
  const int layer = bid >> 5;
  const int w     = bid & 31;
  const int tid   = threadIdx.x;
  const int lane  = tid & 63;
  const int vm    = tid >> 6;
  const int l15   = lane & 15;
  const int lhi   = lane >> 4;
  const int hcol  = w * 16 + l15;
  const int C2r   = (layer == 0) ? 24 : 32;

  const unsigned short* wfl =
      (layer == 0) ? wf0 : (layer == 1) ? wf1 : (layer == 2) ? wf2 : wf3;
  const unsigned short* wsl = wfl + (size_t)w * (4 * C2r * 64 * 8);

  // stage weights into LDS (frag-linear; one-time)
  for (int i = tid; i < 4 * C2r * 64; i += NT)
    *(f32x4*)(smem + (size_t)i * 16) = *(const f32x4*)(wsl + (size_t)i * 8);
  __syncthreads();

  const char* bg[4];
#pragma unroll
  for (int g = 0; g < 4; ++g) bg[g] = smem + ((size_t)g * C2r * 64 + lane) * 16;

  float bv[4];
#pragma unroll
  for (int g = 0; g < 4; ++g) bv[g] = bias[layer * 2048 + g * 512 + hcol];

  float creg[2][4];
#pragma unroll
  for (int m = 0; m < 2; ++m)
#pragma unroll
    for (int r = 0; r < 4; ++r) creg[m][r] = 0.f;

  const int voffA = lane * 16;
  // h fragment base offset for this lane's hcol (shorts):
  // consumer addr = c*2048 + bt*512 + lane_c*8 + e, lane_c = ((hcol>>3)&3)*16 + (b&15)
  const int hfix = (hcol >> 5) * 2048 + ((hcol >> 3) & 3) * 128 + (hcol & 7);

  const unsigned short* hbase_prev =
      (layer == 0) ? nullptr : (hbuf + (size_t)(layer - 1) * RING * 32768);
  const unsigned short* hbase_self = hbuf + (size_t)layer * RING * 32768;

  for (int t = 0; t < 512; ++t) {
    // ---- poll (wave 0, parallel conditions) ----
    if (vm == 0) {
      const unsigned int* fa = &cnt[0];
      unsigned int need = 0;
      if (lane == 0 && layer > 0) { fa = &cnt[(layer - 1) * 512 + t]; need = WPL; }
      if (lane == 1 && t > 0)     { fa = &cnt[layer * 512 + t - 1];   need = WPL; }
      if (lane == 2 && layer < 3 && t >= RING) {
        fa = &cnt[(layer + 1) * 512 + t - RING]; need = WPL;
      }
      while (true) {
        unsigned int v = need ? __hip_atomic_load(fa, __ATOMIC_RELAXED,
                                                  __HIP_MEMORY_SCOPE_AGENT)
                              : 0u;
        if (__ballot(need && v < need) == 0) break;
        __builtin_amdgcn_s_sleep(1);
      }
    }
    __syncthreads();

    const unsigned short* a1 =
        (layer == 0) ? (xfrag + (size_t)t * 16384)
                     : (hbase_prev + (size_t)(t & (RING - 1)) * 32768);
    const unsigned short* a2 =
        hbase_self + (size_t)((t - 1) & (RING - 1)) * 32768;

    f32x4 acc[2][4];
    const f32x4 z4 = {0.f, 0.f, 0.f, 0.f};
#pragma unroll
    for (int m = 0; m < 2; ++m)
#pragma unroll
      for (int g = 0; g < 4; ++g) acc[m][g] = z4;

    if (t == 0) {
      if (layer == 0)
        gemm_run<8, 8, false>(a1, a1, bg[0], bg[1], bg[2], bg[3], voffA, vm, acc);
      else
        gemm_run<16, 16, true>(a1, a1, bg[0], bg[1], bg[2], bg[3], voffA, vm, acc);
    } else {
      if (layer == 0)
        gemm_run<8, 24, false>(a1, a2, bg[0], bg[1], bg[2], bg[3], voffA, vm, acc);
      else
        gemm_run<16, 32, true>(a1, a2, bg[0], bg[1], bg[2], bg[3], voffA, vm, acc);
    }

    // ---- gates + state + fragment-layout coherent h store ----
    unsigned short* hw =
        hbuf + ((size_t)layer * RING + (t & (RING - 1))) * 32768 + hfix;
#pragma unroll
    for (int m = 0; m < 2; ++m) {
#pragma unroll
      for (int r = 0; r < 4; ++r) {
        int bidx = vm * 32 + m * 16 + lhi * 4 + r;
        float fg = sigmoid_fast(acc[m][0][r] + bv[0]);
        float ig = sigmoid_fast(acc[m][1][r] + bv[1]);
        float og = sigmoid_fast(acc[m][2][r] + bv[2]);
        float gg = tanh_fast(acc[m][3][r] + bv[3]);
        float cn = fg * creg[m][r] + ig * gg;
        creg[m][r] = cn;
        float h = og * tanh_fast(cn);
        st2_coh(hw + (vm * 2 + m) * 512 + (lhi * 4 + r) * 8,
                (unsigned int)f2bf(h));
        if (layer == 3)
          out[(size_t)bidx * 262144 + (size_t)t * 512 + hcol] = h;
        if (t == 511) {
          out[16777216 + ((size_t)layer * 64 + bidx) * 512 + hcol] = h;
          out[16777216 + 131072 + ((size_t)layer * 64 + bidx) * 512 + hcol] = cn;
        }
      }
    }
    wait_vm0();
    __syncthreads();
    if (tid == 0)
      __hip_atomic_fetch_add(&cnt[layer * 512 + t], 1u, __ATOMIC_RELAXED,
                             __HIP_MEMORY_SCOPE_AGENT);
  }
}

extern "C" void kernel_launch(void* const* d_in, const int* in_sizes, int n_in,
                              void* d_out, int out_size, void* d_ws, size_t ws_size,
                              hipStream_t stream) {
  const float* x = (const float*)d_in[0];
  const float *W[4], *U[4], *bw[4], *bu[4];
  for (int l = 0; l < 4; ++l) {
    W[l]  = (const float*)d_in[1 + 4 * l];
    U[l]  = (const float*)d_in[2 + 4 * l];
    bw[l] = (const float*)d_in[3 + 4 * l];
    bu[l] = (const float*)d_in[4 + 4 * l];
  }

  char* ws = (char*)d_ws;
  unsigned short* xfrag = (unsigned short*)(ws + 0);        // 16,777,216
  unsigned short* wfr0  = (unsigned short*)(ws + 16777216); //  3,145,728
  unsigned short* wfr1  = (unsigned short*)(ws + 19922944); //  4,194,304
  unsigned short* wfr2  = (unsigned short*)(ws + 24117248); //  4,194,304
  unsigned short* wfr3  = (unsigned short*)(ws + 28311552); //  4,194,304
  float*          biasp = (float*)(ws + 32505856);          //     32,768
  unsigned short* hbuf  = (unsigned short*)(ws + 32538624); //  2,097,152
  unsigned int*   cnt   = (unsigned int*)(ws + 34635776);   //      8,192
  float* out = (float*)d_out;

  cvt_x_kernel<<<4096, 256, 0, stream>>>(x, xfrag);
  cvt_w_kernel<<<768, 256, 0, stream>>>(W[0], U[0], wfr0, 24, 256);
  cvt_w_kernel<<<1024, 256, 0, stream>>>(W[1], U[1], wfr1, 32, 512);
  cvt_w_kernel<<<1024, 256, 0, stream>>>(W[2], U[2], wfr2, 32, 512);
  cvt_w_kernel<<<1024, 256, 0, stream>>>(W[3], U[3], wfr3, 32, 512);
  bias_kernel<<<8, 256, 0, stream>>>(bw[0], bu[0], biasp + 0 * 2048);
  bias_kernel<<<8, 256, 0, stream>>>(bw[1], bu[1], biasp + 1 * 2048);
  bias_kernel<<<8, 256, 0, stream>>>(bw[2], bu[2], biasp + 2 * 2048);
  bias_kernel<<<8, 256, 0, stream>>>(bw[3], bu[3], biasp + 3 * 2048);
  zero_flags<<<8, 256, 0, stream>>>(cnt);

  hipFuncSetAttribute((const void*)lstm_main,
                      hipFuncAttributeMaxDynamicSharedMemorySize, 131072);
  lstm_main<<<dim3(4 * WPL), dim3(NT), 131072, stream>>>(
      xfrag, wfr0, wfr1, wfr2, wfr3, biasp, hbuf, cnt, out);
}

// Round 5
// 1886.346 us; speedup vs baseline: 14.8451x; 1.6209x over previous
//
#include <hip/hip_runtime.h>

typedef __attribute__((ext_vector_type(8))) short bf16x8;
typedef __attribute__((ext_vector_type(4))) float f32x4;

// B=64, T=512, D=256, H=512, L=4, 4H=2048
// 32 wgs per layer (16 hcols each), 256 threads (4 waves) per wg.
#define WPL 32
#define NT 256
#define RING 8

__device__ __forceinline__ unsigned short f2bf(float f) {
  unsigned int u = __float_as_uint(f);
  u += 0x7FFFu + ((u >> 16) & 1u);
  return (unsigned short)(u >> 16);
}
__device__ __forceinline__ float sigmoid_fast(float x) {
  return __builtin_amdgcn_rcpf(1.0f + __builtin_amdgcn_exp2f(-1.4426950408889634f * x));
}
__device__ __forceinline__ float tanh_fast(float x) {
  return 1.0f - 2.0f * __builtin_amdgcn_rcpf(
                           1.0f + __builtin_amdgcn_exp2f(2.885390081777927f * x));
}
__device__ __forceinline__ void wait_vm0() {
  asm volatile("s_waitcnt vmcnt(0)" ::: "memory");
  __builtin_amdgcn_sched_barrier(0);
}
#define WAITVM(N)                                         \
  do {                                                    \
    asm volatile("s_waitcnt vmcnt(" #N ")" ::: "memory"); \
    __builtin_amdgcn_sched_barrier(0);                    \
  } while (0)

// ---------------- prep kernels ----------------

// x [B,T,D] f32 -> xfrag [T][c(8)][bt(4)][lane(64)][e(8)] bf16, lane-linear
__global__ void cvt_x_kernel(const float* __restrict__ x,
                             unsigned short* __restrict__ xf) {
  int tid = blockIdx.x * 256 + threadIdx.x;  // 1,048,576
  int t     = tid >> 11;
  int inner = tid & 2047;
  int lane  = inner & 63;
  int bt    = (inner >> 6) & 3;
  int c     = inner >> 8;
  int b = bt * 16 + (lane & 15);
  int d = c * 32 + (lane >> 4) * 8;
  const float* s = x + ((size_t)b * 512 + t) * 256 + d;
  f32x4 v0 = *(const f32x4*)s;
  f32x4 v1 = *(const f32x4*)(s + 4);
  bf16x8 o;
  o[0] = (short)f2bf(v0[0]); o[1] = (short)f2bf(v0[1]);
  o[2] = (short)f2bf(v0[2]); o[3] = (short)f2bf(v0[3]);
  o[4] = (short)f2bf(v1[0]); o[5] = (short)f2bf(v1[1]);
  o[6] = (short)f2bf(v1[2]); o[7] = (short)f2bf(v1[3]);
  *(bf16x8*)(xf + (size_t)t * 16384 + (size_t)inner * 8) = o;
}

// W/U f32 -> wfrag [w(32)][g(4)][c(C2)][lane(64)][e(8)] bf16
__global__ void cvt_w_kernel(const float* __restrict__ W,
                             const float* __restrict__ U,
                             unsigned short* __restrict__ dst,
                             int C2, int split) {
  int tid = blockIdx.x * 256 + threadIdx.x;
  int lane = tid & 63;
  int c    = (tid >> 6) % C2;
  int rest = tid / (64 * C2);
  int g = rest & 3;
  int w = rest >> 2;
  int row = g * 512 + w * 16 + (lane & 15);
  int k   = c * 32 + (lane >> 4) * 8;
  const float* s = (k < split) ? (W + (size_t)row * split + k)
                               : (U + (size_t)row * 512 + (k - split));
  f32x4 v0 = *(const f32x4*)s;
  f32x4 v1 = *(const f32x4*)(s + 4);
  bf16x8 o;
  o[0] = (short)f2bf(v0[0]); o[1] = (short)f2bf(v0[1]);
  o[2] = (short)f2bf(v0[2]); o[3] = (short)f2bf(v0[3]);
  o[4] = (short)f2bf(v1[0]); o[5] = (short)f2bf(v1[1]);
  o[6] = (short)f2bf(v1[2]); o[7] = (short)f2bf(v1[3]);
  *(bf16x8*)(dst + (size_t)tid * 8) = o;
}

__global__ void bias_kernel(const float* __restrict__ bw,
                            const float* __restrict__ bu,
                            float* __restrict__ dst) {
  int i = blockIdx.x * 256 + threadIdx.x;  // 2048
  dst[i] = bw[i] + bu[i];
}

__global__ void zero_flags(unsigned int* __restrict__ p) {
  int i = blockIdx.x * 256 + threadIdx.x;  // 2048 (4*32 flags, 64B padded)
  p[i] = 0u;
}

// ---------------- pipelined per-step GEMM ----------------
// A from global frag layout; B from LDS frag layout. 3-phase-deep A pipeline,
// counted vmcnt (4 loads/phase); double-buffered B.
template <int C1, int C2, bool COH1>
__device__ __forceinline__ void gemm_run(const unsigned short* __restrict__ a1,
                                         const unsigned short* __restrict__ a2,
                                         const char* bg0, const char* bg1,
                                         const char* bg2, const char* bg3,
                                         int voffA, f32x4 acc[4]) {
  constexpr int NP = C2 / 4;
  bf16x8 av[3][4];
  bf16x8 bb[2][4][4];
  const char* bgp[4] = {bg0, bg1, bg2, bg3};

  auto issueA_iter = [&](int cc, int s3, int i) {
    if (cc < C1) {
      int voff = voffA + cc * 4096;
      if constexpr (COH1)
        asm volatile("global_load_dwordx4 %0, %1, %2 sc0 sc1"
                     : "=v"(av[s3][i]) : "v"(voff), "s"(a1));
      else
        asm volatile("global_load_dwordx4 %0, %1, %2"
                     : "=v"(av[s3][i]) : "v"(voff), "s"(a1));
    } else {
      int voff = voffA + (cc - C1) * 4096;
      asm volatile("global_load_dwordx4 %0, %1, %2 sc0 sc1"
                   : "=v"(av[s3][i]) : "v"(voff), "s"(a2));
    }
  };
  auto issueA_phase = [&](int q) {
#pragma unroll
    for (int i = 0; i < 4; ++i) issueA_iter(4 * q + i, q % 3, i);
  };
  auto loadB_phase = [&](int q) {
#pragma unroll
    for (int i = 0; i < 4; ++i)
#pragma unroll
      for (int g = 0; g < 4; ++g)
        bb[q & 1][i][g] = *(const bf16x8*)(bgp[g] + (4 * q + i) * 1024);
  };

#pragma unroll
  for (int q = 0; q < 3; ++q)
    if (q < NP) issueA_phase(q);
  loadB_phase(0);

#pragma unroll
  for (int ph = 0; ph < NP; ++ph) {
    if (ph + 1 < NP) loadB_phase(ph + 1);
    if (ph < NP - 2) {
      WAITVM(8);
    } else if (ph == NP - 2) {
      WAITVM(4);
    } else {
      WAITVM(0);
    }
#pragma unroll
    for (int i = 0; i < 4; ++i)
#pragma unroll
      for (int g = 0; g < 4; ++g)
        acc[g] = __builtin_amdgcn_mfma_f32_16x16x32_bf16(av[ph % 3][i],
                                                         bb[ph & 1][i][g],
                                                         acc[g], 0, 0, 0);
    if (ph + 3 < NP) issueA_phase(ph + 3);
  }
}

// ---------------- main persistent kernel ----------------
// grid 128: layer = bid>>5, w = bid&31 (hcols w*16..+16).
// 4 waves: wave vm owns m-tile rows vm*16..+16, full K.
__global__ void __launch_bounds__(NT, 1)
lstm_main(const unsigned short* __restrict__ xfrag,
          const unsigned short* __restrict__ wf0,
          const unsigned short* __restrict__ wf1,
          const unsigned short* __restrict__ wf2,
          const unsigned short* __restrict__ wf3,
          const float* __restrict__ bias,
          unsigned short* __restrict__ hbuf,
          unsigned int* __restrict__ flags,
          float* __restrict__ out) {
  extern __shared__ char smem[];

  const int bid   = blockIdx.x;
  const int layer = bid >> 5;
  const int w     = bid & 31;
  const int tid   = threadIdx.x;
  const int lane  = tid & 63;
  const int vm    = tid >> 6;
  const int l15   = lane & 15;
  const int lhi   = lane >> 4;
  const int hcol  = w * 16 + l15;
  const int C2r   = (layer == 0) ? 24 : 32;
  const int HOFF  = 4 * C2r * 64 * 16;  // LDS h-transpose buffer offset

  const unsigned short* wfl =
      (layer == 0) ? wf0 : (layer == 1) ? wf1 : (layer == 2) ? wf2 : wf3;
  const unsigned short* wsl = wfl + (size_t)w * (4 * C2r * 64 * 8);

  for (int i = tid; i < 4 * C2r * 64; i += NT)
    *(f32x4*)(smem + (size_t)i * 16) = *(const f32x4*)(wsl + (size_t)i * 8);
  __syncthreads();

  const char* bg[4];
#pragma unroll
  for (int g = 0; g < 4; ++g) bg[g] = smem + ((size_t)g * C2r * 64 + lane) * 16;

  float bv[4];
#pragma unroll
  for (int g = 0; g < 4; ++g) bv[g] = bias[layer * 2048 + g * 512 + hcol];

  float creg[4];
#pragma unroll
  for (int r = 0; r < 4; ++r) creg[r] = 0.f;

  const int voffA = lane * 16 + vm * 1024;
  const int base_w = (w >> 1) * 2048 + (w & 1) * 256;  // shorts, h publish base

  const unsigned short* hbase_prev =
      (layer == 0) ? nullptr : (hbuf + (size_t)(layer - 1) * RING * 32768);
  const unsigned short* hbase_self = hbuf + (size_t)layer * RING * 32768;

  // h publish store thread mapping (tid < 128)
  const int sb_bt = tid >> 5;
  const int sb_q  = (tid >> 4) & 1;
  const int sb_bl = tid & 15;

  for (int t = 0; t < 512; ++t) {
    // ---- poll: wave0 = forward deps (parallel lanes); wave1 = ring credit ----
    if (vm == 0) {
      const unsigned int* fp = flags;
      unsigned int need = 0;
      if (lane < 32) {
        if (layer > 0) { fp = flags + ((layer - 1) * 32 + lane) * 16; need = (unsigned)(t + 1); }
      } else {
        if (t > 0) { fp = flags + (layer * 32 + (lane - 32)) * 16; need = (unsigned)t; }
      }
      while (true) {
        unsigned int v = need ? __hip_atomic_load(fp, __ATOMIC_RELAXED,
                                                  __HIP_MEMORY_SCOPE_AGENT) : 0u;
        if (__ballot(need && v < need) == 0) break;
        __builtin_amdgcn_s_sleep(1);
      }
    } else if (vm == 1) {
      const unsigned int* fp = flags;
      unsigned int need = 0;
      if (lane < 32 && layer < 3 && t >= RING) {
        fp = flags + ((layer + 1) * 32 + lane) * 16;
        need = (unsigned)(t - RING + 1);
      }
      while (true) {
        unsigned int v = need ? __hip_atomic_load(fp, __ATOMIC_RELAXED,
                                                  __HIP_MEMORY_SCOPE_AGENT) : 0u;
        if (__ballot(need && v < need) == 0) break;
        __builtin_amdgcn_s_sleep(1);
      }
    }
    __syncthreads();

    const unsigned short* a1 =
        (layer == 0) ? (xfrag + (size_t)t * 16384)
                     : (hbase_prev + (size_t)(t & (RING - 1)) * 32768);
    const unsigned short* a2 =
        hbase_self + (size_t)((t - 1) & (RING - 1)) * 32768;

    f32x4 acc[4];
    const f32x4 z4 = {0.f, 0.f, 0.f, 0.f};
#pragma unroll
    for (int g = 0; g < 4; ++g) acc[g] = z4;

    if (t == 0) {
      if (layer == 0)
        gemm_run<8, 8, false>(a1, a1, bg[0], bg[1], bg[2], bg[3], voffA, acc);
      else
        gemm_run<16, 16, true>(a1, a1, bg[0], bg[1], bg[2], bg[3], voffA, acc);
    } else {
      if (layer == 0)
        gemm_run<8, 24, false>(a1, a2, bg[0], bg[1], bg[2], bg[3], voffA, acc);
      else
        gemm_run<16, 32, true>(a1, a2, bg[0], bg[1], bg[2], bg[3], voffA, acc);
    }

    // ---- gates + state; h -> LDS transpose ----
    float hreg[4], cnreg[4];
#pragma unroll
    for (int r = 0; r < 4; ++r) {
      float fg = sigmoid_fast(acc[0][r] + bv[0]);
      float ig = sigmoid_fast(acc[1][r] + bv[1]);
      float og = sigmoid_fast(acc[2][r] + bv[2]);
      float gg = tanh_fast(acc[3][r] + bv[3]);
      float cn = fg * creg[r] + ig * gg;
      creg[r] = cn;
      cnreg[r] = cn;
      float h = og * tanh_fast(cn);
      hreg[r] = h;
      *(unsigned short*)(smem + HOFF + (vm * 16 + lhi * 4 + r) * 32 + l15 * 2) =
          f2bf(h);
    }
    __syncthreads();

    // ---- coalesced coherent h publish (threads 0..127) ----
    if (tid < 128) {
      f32x4 hv = *(const f32x4*)(smem + HOFF + (sb_bt * 16 + sb_bl) * 32 + sb_q * 16);
      unsigned short* dst = hbuf +
          ((size_t)layer * RING + (t & (RING - 1))) * 32768 +
          base_w + sb_bt * 512 + sb_q * 128 + sb_bl * 8;
      asm volatile("global_store_dwordx4 %0, %1, off sc0 sc1"
                   :: "v"(dst), "v"(hv) : "memory");
      wait_vm0();
    }
    __syncthreads();
    if (tid == 0)
      __hip_atomic_store(flags + (layer * 32 + w) * 16, (unsigned)(t + 1),
                         __ATOMIC_RELAXED, __HIP_MEMORY_SCOPE_AGENT);

    // ---- output stores (off the critical chain) ----
    if (layer == 3) {
#pragma unroll
      for (int r = 0; r < 4; ++r) {
        int bidx = vm * 16 + lhi * 4 + r;
        out[(size_t)bidx * 262144 + (size_t)t * 512 + hcol] = hreg[r];
      }
    }
    if (t == 511) {
#pragma unroll
      for (int r = 0; r < 4; ++r) {
        int bidx = vm * 16 + lhi * 4 + r;
        out[16777216 + ((size_t)layer * 64 + bidx) * 512 + hcol] = hreg[r];
        out[16777216 + 131072 + ((size_t)layer * 64 + bidx) * 512 + hcol] = cnreg[r];
      }
    }
  }
}

extern "C" void kernel_launch(void* const* d_in, const int* in_sizes, int n_in,
                              void* d_out, int out_size, void* d_ws, size_t ws_size,
                              hipStream_t stream) {
  const float* x = (const float*)d_in[0];
  const float *W[4], *U[4], *bw[4], *bu[4];
  for (int l = 0; l < 4; ++l) {
    W[l]  = (const float*)d_in[1 + 4 * l];
    U[l]  = (const float*)d_in[2 + 4 * l];
    bw[l] = (const float*)d_in[3 + 4 * l];
    bu[l] = (const float*)d_in[4 + 4 * l];
  }

  char* ws = (char*)d_ws;
  unsigned short* xfrag = (unsigned short*)(ws + 0);        // 16,777,216
  unsigned short* wfr0  = (unsigned short*)(ws + 16777216); //  3,145,728
  unsigned short* wfr1  = (unsigned short*)(ws + 19922944); //  4,194,304
  unsigned short* wfr2  = (unsigned short*)(ws + 24117248); //  4,194,304
  unsigned short* wfr3  = (unsigned short*)(ws + 28311552); //  4,194,304
  float*          biasp = (float*)(ws + 32505856);          //     32,768
  unsigned short* hbuf  = (unsigned short*)(ws + 32538624); //  2,097,152
  unsigned int*   flags = (unsigned int*)(ws + 34635776);   //      8,192
  float* out = (float*)d_out;

  cvt_x_kernel<<<4096, 256, 0, stream>>>(x, xfrag);
  cvt_w_kernel<<<768, 256, 0, stream>>>(W[0], U[0], wfr0, 24, 256);
  cvt_w_kernel<<<1024, 256, 0, stream>>>(W[1], U[1], wfr1, 32, 512);
  cvt_w_kernel<<<1024, 256, 0, stream>>>(W[2], U[2], wfr2, 32, 512);
  cvt_w_kernel<<<1024, 256, 0, stream>>>(W[3], U[3], wfr3, 32, 512);
  bias_kernel<<<8, 256, 0, stream>>>(bw[0], bu[0], biasp + 0 * 2048);
  bias_kernel<<<8, 256, 0, stream>>>(bw[1], bu[1], biasp + 1 * 2048);
  bias_kernel<<<8, 256, 0, stream>>>(bw[2], bu[2], biasp + 2 * 2048);
  bias_kernel<<<8, 256, 0, stream>>>(bw[3], bu[3], biasp + 3 * 2048);
  zero_flags<<<8, 256, 0, stream>>>(flags);

  hipFuncSetAttribute((const void*)lstm_main,
                      hipFuncAttributeMaxDynamicSharedMemorySize, 135168);
  lstm_main<<<dim3(4 * WPL), dim3(NT), 135168, stream>>>(
      xfrag, wfr0, wfr1, wfr2, wfr3, biasp, hbuf, flags, out);
}

// Round 8
// 1853.514 us; speedup vs baseline: 15.1080x; 1.0177x over previous
//
#include <hip/hip_runtime.h>

typedef __attribute__((ext_vector_type(8))) short bf16x8;
typedef __attribute__((ext_vector_type(4))) float f32x4;

// B=64, T=512, D=256, H=512, L=4, 4H=2048
// 32 wgs per layer (16 hcols each), 256 threads (4 waves) per wg. Grid 128.
// All h/flag exchange via LLC (sc0 sc1) — the round-5 proven protocol.
// New in v8: per-step split schedule W-GEMM | self-poll | U-GEMM so the
// self-dependency flag latency hides under the W-part matmul.
#define WPL 32
#define NT 256
#define RING 8

__device__ __forceinline__ unsigned short f2bf(float f) {
  unsigned int u = __float_as_uint(f);
  u += 0x7FFFu + ((u >> 16) & 1u);
  return (unsigned short)(u >> 16);
}
__device__ __forceinline__ float sigmoid_fast(float x) {
  return __builtin_amdgcn_rcpf(1.0f + __builtin_amdgcn_exp2f(-1.4426950408889634f * x));
}
__device__ __forceinline__ float tanh_fast(float x) {
  return 1.0f - 2.0f * __builtin_amdgcn_rcpf(
                           1.0f + __builtin_amdgcn_exp2f(2.885390081777927f * x));
}
__device__ __forceinline__ void wait_vm0() {
  asm volatile("s_waitcnt vmcnt(0)" ::: "memory");
  __builtin_amdgcn_sched_barrier(0);
}
#define WAITVM(N)                                         \
  do {                                                    \
    asm volatile("s_waitcnt vmcnt(" #N ")" ::: "memory"); \
    __builtin_amdgcn_sched_barrier(0);                    \
  } while (0)

// MODE: 0 = plain cached (read-only x), 2 = sc0 sc1 (LLC coherent h)
template <int MODE>
__device__ __forceinline__ void ldA(bf16x8& d, int voff, const unsigned short* base) {
  if constexpr (MODE == 0)
    asm volatile("global_load_dwordx4 %0, %1, %2"
                 : "=v"(d) : "v"(voff), "s"(base));
  else
    asm volatile("global_load_dwordx4 %0, %1, %2 sc0 sc1"
                 : "=v"(d) : "v"(voff), "s"(base));
}
__device__ __forceinline__ unsigned ld_flag(const unsigned* p) {
  unsigned v;
  asm volatile("global_load_dword %0, %1, off sc0 sc1\n\ts_waitcnt vmcnt(0)"
               : "=v"(v) : "v"(p) : "memory");
  return v;
}
__device__ __forceinline__ void st16_coh(void* p, f32x4 v) {
  asm volatile("global_store_dwordx4 %0, %1, off sc0 sc1" :: "v"(p), "v"(v) : "memory");
}
__device__ __forceinline__ void st4_coh(void* p, unsigned v) {
  asm volatile("global_store_dword %0, %1, off sc0 sc1" :: "v"(p), "v"(v) : "memory");
}

// ---------------- prep kernels ----------------

// x [B,T,D] f32 -> xfrag [T][c(8)][bt(4)][lane(64)][e(8)] bf16, lane-linear
__global__ void cvt_x_kernel(const float* __restrict__ x,
                             unsigned short* __restrict__ xf) {
  int tid = blockIdx.x * 256 + threadIdx.x;  // 1,048,576
  int t     = tid >> 11;
  int inner = tid & 2047;
  int lane  = inner & 63;
  int bt    = (inner >> 6) & 3;
  int c     = inner >> 8;
  int b = bt * 16 + (lane & 15);
  int d = c * 32 + (lane >> 4) * 8;
  const float* s = x + ((size_t)b * 512 + t) * 256 + d;
  f32x4 v0 = *(const f32x4*)s;
  f32x4 v1 = *(const f32x4*)(s + 4);
  bf16x8 o;
  o[0] = (short)f2bf(v0[0]); o[1] = (short)f2bf(v0[1]);
  o[2] = (short)f2bf(v0[2]); o[3] = (short)f2bf(v0[3]);
  o[4] = (short)f2bf(v1[0]); o[5] = (short)f2bf(v1[1]);
  o[6] = (short)f2bf(v1[2]); o[7] = (short)f2bf(v1[3]);
  *(bf16x8*)(xf + (size_t)t * 16384 + (size_t)inner * 8) = o;
}

// W/U f32 -> wfrag [w(32)][g(4)][c(C2)][lane(64)][e(8)] bf16
__global__ void cvt_w_kernel(const float* __restrict__ W,
                             const float* __restrict__ U,
                             unsigned short* __restrict__ dst,
                             int C2, int split) {
  int tid = blockIdx.x * 256 + threadIdx.x;
  int lane = tid & 63;
  int c    = (tid >> 6) % C2;
  int rest = tid / (64 * C2);
  int g = rest & 3;
  int w = rest >> 2;
  int row = g * 512 + w * 16 + (lane & 15);
  int k   = c * 32 + (lane >> 4) * 8;
  const float* s = (k < split) ? (W + (size_t)row * split + k)
                               : (U + (size_t)row * 512 + (k - split));
  f32x4 v0 = *(const f32x4*)s;
  f32x4 v1 = *(const f32x4*)(s + 4);
  bf16x8 o;
  o[0] = (short)f2bf(v0[0]); o[1] = (short)f2bf(v0[1]);
  o[2] = (short)f2bf(v0[2]); o[3] = (short)f2bf(v0[3]);
  o[4] = (short)f2bf(v1[0]); o[5] = (short)f2bf(v1[1]);
  o[6] = (short)f2bf(v1[2]); o[7] = (short)f2bf(v1[3]);
  *(bf16x8*)(dst + (size_t)tid * 8) = o;
}

__global__ void bias_kernel(const float* __restrict__ bw,
                            const float* __restrict__ bu,
                            float* __restrict__ dst) {
  int i = blockIdx.x * 256 + threadIdx.x;  // 2048
  dst[i] = bw[i] + bu[i];
}

__global__ void zero_flags(unsigned int* __restrict__ p) {
  int i = blockIdx.x * 256 + threadIdx.x;  // 2048
  p[i] = 0u;
}

// ---------------- pipelined partial GEMM (NC k-chunks from one base) ----------------
// A from global frag layout; B from LDS frag layout (bg pre-offset by caller).
// 3-phase-deep A pipeline with counted vmcnt. Requires vmcnt==0 at entry;
// leaves vmcnt==0 at exit.
template <int NC, int MODE>
__device__ __forceinline__ void gemm_part(const unsigned short* __restrict__ a,
                                          const char* bg0, const char* bg1,
                                          const char* bg2, const char* bg3,
                                          int voffA, f32x4 acc[4]) {
  constexpr int NP = NC / 4;
  bf16x8 av[3][4];
  bf16x8 bb[2][4][4];
  const char* bgp[4] = {bg0, bg1, bg2, bg3};

  auto issueA_phase = [&](int q) {
#pragma unroll
    for (int i = 0; i < 4; ++i)
      ldA<MODE>(av[q % 3][i], voffA + (4 * q + i) * 4096, a);
  };
  auto loadB_phase = [&](int q) {
#pragma unroll
    for (int i = 0; i < 4; ++i)
#pragma unroll
      for (int g = 0; g < 4; ++g)
        bb[q & 1][i][g] = *(const bf16x8*)(bgp[g] + (4 * q + i) * 1024);
  };

#pragma unroll
  for (int q = 0; q < 3; ++q)
    if (q < NP) issueA_phase(q);
  loadB_phase(0);

#pragma unroll
  for (int ph = 0; ph < NP; ++ph) {
    if (ph + 1 < NP) loadB_phase(ph + 1);
    if (ph < NP - 2) {
      WAITVM(8);
    } else if (ph == NP - 2) {
      WAITVM(4);
    } else {
      WAITVM(0);
    }
#pragma unroll
    for (int i = 0; i < 4; ++i)
#pragma unroll
      for (int g = 0; g < 4; ++g)
        acc[g] = __builtin_amdgcn_mfma_f32_16x16x32_bf16(av[ph % 3][i],
                                                         bb[ph & 1][i][g],
                                                         acc[g], 0, 0, 0);
    if (ph + 3 < NP) issueA_phase(ph + 3);
  }
}

// ---------------- main persistent kernel ----------------
// grid 128: layer = bid>>5, w = bid&31 (hcols w*16..+16).
// 4 waves: wave vm owns m-tile rows vm*16..+16, full K.
__global__ void __launch_bounds__(NT, 1)
lstm_main(const unsigned short* __restrict__ xfrag,
          const unsigned short* __restrict__ wf0,
          const unsigned short* __restrict__ wf1,
          const unsigned short* __restrict__ wf2,
          const unsigned short* __restrict__ wf3,
          const float* __restrict__ bias,
          unsigned short* __restrict__ hbuf,
          unsigned int* __restrict__ flags,
          float* __restrict__ out) {
  extern __shared__ char smem[];

  const int bid   = blockIdx.x;
  const int layer = bid >> 5;
  const int w     = bid & 31;
  const int tid   = threadIdx.x;
  const int lane  = tid & 63;
  const int vm    = tid >> 6;
  const int l15   = lane & 15;
  const int lhi   = lane >> 4;
  const int hcol  = w * 16 + l15;
  const int C2r   = (layer == 0) ? 24 : 32;
  const int C1w   = (layer == 0) ? 8 : 16;   // W-part chunks
  const int HOFF  = 4 * C2r * 64 * 16;       // LDS h-transpose buffer offset

  const unsigned short* wfl =
      (layer == 0) ? wf0 : (layer == 1) ? wf1 : (layer == 2) ? wf2 : wf3;
  const unsigned short* wsl = wfl + (size_t)w * (4 * C2r * 64 * 8);

  // stage weights into LDS (frag-linear; one-time)
  for (int i = tid; i < 4 * C2r * 64; i += NT)
    *(f32x4*)(smem + (size_t)i * 16) = *(const f32x4*)(wsl + (size_t)i * 8);
  __syncthreads();

  const char* bgW[4];
  const char* bgU[4];
#pragma unroll
  for (int g = 0; g < 4; ++g) {
    bgW[g] = smem + ((size_t)g * C2r * 64 + lane) * 16;
    bgU[g] = bgW[g] + (size_t)C1w * 1024;
  }

  float bv[4];
#pragma unroll
  for (int g = 0; g < 4; ++g) bv[g] = bias[layer * 2048 + g * 512 + hcol];

  float creg[4];
#pragma unroll
  for (int r = 0; r < 4; ++r) creg[r] = 0.f;

  const int voffA = lane * 16 + vm * 1024;
  const int base_w = (w >> 1) * 2048 + (w & 1) * 256;  // shorts

  const unsigned short* hprev =
      (layer == 0) ? nullptr : (hbuf + (size_t)(layer - 1) * RING * 32768);
  const unsigned short* hself = hbuf + (size_t)layer * RING * 32768;

  // h publish store thread mapping (tid < 128)
  const int sb_bt = tid >> 5;
  const int sb_q  = (tid >> 4) & 1;
  const int sb_bl = tid & 15;
  const int slot_off = base_w + sb_bt * 512 + sb_q * 128 + sb_bl * 8;

  for (int t = 0; t < 512; ++t) {
    // ---- barrier A: cross-dep (wave0) + ring credit (wave1) ----
    if (vm == 0) {
      const unsigned* fp = flags;
      unsigned need = 0;
      if (lane < 32 && layer > 0) {
        fp = flags + ((layer - 1) * 32 + lane) * 16;
        need = (unsigned)(t + 1);
      }
      while (true) {
        unsigned v = need ? ld_flag(fp) : 0u;
        if (__ballot(need && v < need) == 0) break;
        __builtin_amdgcn_s_sleep(1);
      }
    } else if (vm == 1) {
      const unsigned* fp = flags;
      unsigned need = 0;
      if (lane < 32 && layer < 3 && t >= RING) {
        fp = flags + ((layer + 1) * 32 + lane) * 16;
        need = (unsigned)(t - RING + 1);
      }
      while (true) {
        unsigned v = need ? ld_flag(fp) : 0u;
        if (__ballot(need && v < need) == 0) break;
        __builtin_amdgcn_s_sleep(1);
      }
    }
    __syncthreads();
    wait_vm0();  // drain stray (out[]) stores so counted vmcnt is exact

    f32x4 acc[4];
    const f32x4 z4 = {0.f, 0.f, 0.f, 0.f};
#pragma unroll
    for (int g = 0; g < 4; ++g) acc[g] = z4;

    // ---- W-part GEMM (cross/x input only) ----
    if (layer == 0)
      gemm_part<8, 0>(xfrag + (size_t)t * 16384,
                      bgW[0], bgW[1], bgW[2], bgW[3], voffA, acc);
    else
      gemm_part<16, 2>(hprev + (size_t)(t & (RING - 1)) * 32768,
                       bgW[0], bgW[1], bgW[2], bgW[3], voffA, acc);

    // ---- barrier B: self-dep poll (hidden under W-part above) ----
    if (t > 0) {
      if (vm == 0) {
        const unsigned* fp = flags;
        unsigned need = 0;
        if (lane < 32) {
          fp = flags + (layer * 32 + lane) * 16;
          need = (unsigned)t;
        }
        while (true) {
          unsigned v = need ? ld_flag(fp) : 0u;
          if (__ballot(need && v < need) == 0) break;
          __builtin_amdgcn_s_sleep(1);
        }
      }
      __syncthreads();

      // ---- U-part GEMM (self h(t-1)) ----
      gemm_part<16, 2>(hself + (size_t)((t - 1) & (RING - 1)) * 32768,
                       bgU[0], bgU[1], bgU[2], bgU[3], voffA, acc);
    }

    // ---- gates + state; h -> LDS transpose ----
    float hreg[4], cnreg[4];
#pragma unroll
    for (int r = 0; r < 4; ++r) {
      float fg = sigmoid_fast(acc[0][r] + bv[0]);
      float ig = sigmoid_fast(acc[1][r] + bv[1]);
      float og = sigmoid_fast(acc[2][r] + bv[2]);
      float gg = tanh_fast(acc[3][r] + bv[3]);
      float cn = fg * creg[r] + ig * gg;
      creg[r] = cn;
      cnreg[r] = cn;
      float h = og * tanh_fast(cn);
      hreg[r] = h;
      *(unsigned short*)(smem + HOFF + (vm * 16 + lhi * 4 + r) * 32 + l15 * 2) =
          f2bf(h);
    }
    __syncthreads();

    // ---- coalesced coherent h publish (threads 0..127) ----
    if (tid < 128) {
      f32x4 hv = *(const f32x4*)(smem + HOFF + (sb_bt * 16 + sb_bl) * 32 + sb_q * 16);
      unsigned short* dst = hbuf +
          ((size_t)layer * RING + (t & (RING - 1))) * 32768 + slot_off;
      st16_coh(dst, hv);
      wait_vm0();
    }
    __syncthreads();
    if (tid == 0)
      st4_coh(flags + (layer * 32 + w) * 16, (unsigned)(t + 1));

    // ---- output stores (off the critical chain) ----
    if (layer == 3) {
#pragma unroll
      for (int r = 0; r < 4; ++r) {
        int bidx = vm * 16 + lhi * 4 + r;
        out[(size_t)bidx * 262144 + (size_t)t * 512 + hcol] = hreg[r];
      }
    }
    if (t == 511) {
#pragma unroll
      for (int r = 0; r < 4; ++r) {
        int bidx = vm * 16 + lhi * 4 + r;
        out[16777216 + ((size_t)layer * 64 + bidx) * 512 + hcol] = hreg[r];
        out[16777216 + 131072 + ((size_t)layer * 64 + bidx) * 512 + hcol] = cnreg[r];
      }
    }
  }
}

extern "C" void kernel_launch(void* const* d_in, const int* in_sizes, int n_in,
                              void* d_out, int out_size, void* d_ws, size_t ws_size,
                              hipStream_t stream) {
  const float* x = (const float*)d_in[0];
  const float *W[4], *U[4], *bw[4], *bu[4];
  for (int l = 0; l < 4; ++l) {
    W[l]  = (const float*)d_in[1 + 4 * l];
    U[l]  = (const float*)d_in[2 + 4 * l];
    bw[l] = (const float*)d_in[3 + 4 * l];
    bu[l] = (const float*)d_in[4 + 4 * l];
  }

  char* ws = (char*)d_ws;
  unsigned short* xfrag = (unsigned short*)(ws + 0);        // 16,777,216
  unsigned short* wfr0  = (unsigned short*)(ws + 16777216); //  3,145,728
  unsigned short* wfr1  = (unsigned short*)(ws + 19922944); //  4,194,304
  unsigned short* wfr2  = (unsigned short*)(ws + 24117248); //  4,194,304
  unsigned short* wfr3  = (unsigned short*)(ws + 28311552); //  4,194,304
  float*          biasp = (float*)(ws + 32505856);          //     32,768
  unsigned short* hbuf  = (unsigned short*)(ws + 32538624); //  2,097,152
  unsigned int*   flags = (unsigned int*)(ws + 34635776);   //      8,192
  float* out = (float*)d_out;

  cvt_x_kernel<<<4096, 256, 0, stream>>>(x, xfrag);
  cvt_w_kernel<<<768, 256, 0, stream>>>(W[0], U[0], wfr0, 24, 256);
  cvt_w_kernel<<<1024, 256, 0, stream>>>(W[1], U[1], wfr1, 32, 512);
  cvt_w_kernel<<<1024, 256, 0, stream>>>(W[2], U[2], wfr2, 32, 512);
  cvt_w_kernel<<<1024, 256, 0, stream>>>(W[3], U[3], wfr3, 32, 512);
  bias_kernel<<<8, 256, 0, stream>>>(bw[0], bu[0], biasp + 0 * 2048);
  bias_kernel<<<8, 256, 0, stream>>>(bw[1], bu[1], biasp + 1 * 2048);
  bias_kernel<<<8, 256, 0, stream>>>(bw[2], bu[2], biasp + 2 * 2048);
  bias_kernel<<<8, 256, 0, stream>>>(bw[3], bu[3], biasp + 3 * 2048);
  zero_flags<<<8, 256, 0, stream>>>(flags);

  hipFuncSetAttribute((const void*)lstm_main,
                      hipFuncAttributeMaxDynamicSharedMemorySize, 135168);
  lstm_main<<<dim3(4 * WPL), dim3(NT), 135168, stream>>>(
      xfrag, wfr0, wfr1, wfr2, wfr3, biasp, hbuf, flags, out);
}